// Round 6
// baseline (654.961 us; speedup 1.0000x reference)
//
#include <hip/hip_runtime.h>
#include <hip/hip_bf16.h>
#include <math.h>

#define Bn 16
#define Tn 2048
#define Wn 10
constexpr float PI_F = 3.14159265358979323846f;

typedef __bf16 bf16x8 __attribute__((ext_vector_type(8)));
typedef float  f32x4  __attribute__((ext_vector_type(4)));

// ---- output offsets (floats) ----
constexpr size_t O_EMB   = 0;
constexpr size_t O_PSPEC = (size_t)Bn*Tn*256;            // 8388608
constexpr size_t O_PPAR  = O_PSPEC + (size_t)Bn*Tn*20;   // 9043968
constexpr size_t O_TSPEC = O_PPAR + 2*Bn;                // 9044000
constexpr size_t O_TPAR  = O_TSPEC + (size_t)Bn*Tn*20;   // 9699360

// ---- workspace BYTE offsets ----
constexpr size_t OB_WB1 = 0;                              // 24 slices x 16KB LDS image
constexpr size_t OB_WB2 = OB_WB1 + 393216;
constexpr size_t OB_H1  = OB_WB2 + 393216;                // B*T*256 bf16
constexpr size_t OB_MS  = OB_H1 + 16777216;               // 32 f32
constexpr size_t OB_X   = OB_MS + 128;                    // B*1024*2 f32
constexpr size_t OB_Z   = OB_X + 131072;                  // B*1024*20 f32
constexpr size_t OB_P2  = OB_Z + 1310720;                 // B*T*2 f32
constexpr size_t OB_WP  = OB_P2 + 262144;                 // 4*B*T*20 f32

__device__ __forceinline__ void gld_lds16(const void* g, void* l){
  __builtin_amdgcn_global_load_lds(
      (const __attribute__((address_space(1))) unsigned int*)g,
      (__attribute__((address_space(3))) unsigned int*)l, 16, 0, 0);
}

// ---- weight prep: w[o][i][k3] fp32 -> per-K-step LDS images in ws ----
__global__ void k_prep_w(const float* __restrict__ w1, const float* __restrict__ w2,
                         char* __restrict__ wb1, char* __restrict__ wb2){
  int idx = blockIdx.x*256 + threadIdx.x;     // 2 * 196608
  const float* w = w1; char* wb = wb1;
  if (idx >= 196608){ idx -= 196608; w = w2; wb = wb2; }
  int s   = idx >> 13;          // 8192 elements per slice
  int rem = idx & 8191;
  int o   = rem >> 5;
  int kk  = rem & 31;
  int k3  = s >> 3;
  int i   = (s & 7)*32 + kk;
  float v = w[((size_t)o*256 + i)*3 + k3];
  size_t off = (size_t)s*16384 + o*64 + ((((kk>>3)<<4)) ^ ((o&6)<<3)) + ((kk&7)<<1);
  *(__bf16*)(wb + off) = (__bf16)v;
}

// ---------------- per-batch stats ----------------
__global__ void k_stats(const float* __restrict__ target, const int* __restrict__ mel,
                        float* __restrict__ msbuf, float* __restrict__ tpar){
  __shared__ float red[256];
  __shared__ float mean_sh;
  int b = blockIdx.x, tid = threadIdx.x;
  const float* tg = target + (size_t)b*Tn;
  int len = mel[b];
  float lenf = (float)len;
  float s = 0.f;
  for (int t=tid; t<Tn; t+=256) s += tg[t];
  red[tid]=s; __syncthreads();
  for (int off=128; off; off>>=1){ if(tid<off) red[tid]+=red[tid+off]; __syncthreads(); }
  if (tid==0) mean_sh = red[0]/lenf;
  __syncthreads();
  float mean = mean_sh;
  float s2 = 0.f;
  for (int t=tid; t<Tn; t+=256){ float d = (t<len)?(tg[t]-mean):0.f; s2 += d*d; }
  red[tid]=s2; __syncthreads();
  for (int off=128; off; off>>=1){ if(tid<off) red[tid]+=red[tid+off]; __syncthreads(); }
  if (tid==0){
    float stdv = sqrtf(red[0]/(lenf-1.f));
    msbuf[2*b]=mean; msbuf[2*b+1]=stdv;
    tpar[2*b]=mean;  tpar[2*b+1]=stdv;
  }
}

// ---------------- forward DFT ----------------
__global__ void k_fwd_dft(const float* __restrict__ target, const int* __restrict__ mel,
                          const float* __restrict__ msbuf, float* __restrict__ X){
  __shared__ float cbuf[Tn];
  __shared__ float2 tw[Tn];
  int b = blockIdx.x >> 6, kc = blockIdx.x & 63, tid = threadIdx.x;
  int len = mel[b];
  float mean = msbuf[2*b];
  float istd = 1.f / msbuf[2*b+1];
  for (int n=tid; n<Tn; n+=256){
    float sn, cs;
    sincosf((2.f*PI_F/Tn)*n, &sn, &cs);
    tw[n] = make_float2(cs, sn);
    cbuf[n] = (n<len) ? (target[(size_t)b*Tn+n]-mean)*istd : 0.f;
  }
  __syncthreads();
  int k  = (kc<<4) | (tid>>4);
  int tl = tid & 15;
  float xr=0.f, xi=0.f;
  for (int t=tl; t<Tn; t+=16){
    int n = (k*t) & (Tn-1);
    float2 w = tw[n];
    float cv = cbuf[t];
    xr += cv*w.x;
    xi -= cv*w.y;
  }
  #pragma unroll
  for (int m=1; m<16; m<<=1){ xr += __shfl_xor(xr,m); xi += __shfl_xor(xi,m); }
  if (tl==0){ X[2*(b*1024+k)] = xr; X[2*(b*1024+k)+1] = xi; }
}

// ---------------- Z = X * psi_hat / T ----------------
__global__ void k_zmul(const float* __restrict__ X, float* __restrict__ Z){
  int idx = blockIdx.x*256 + threadIdx.x;  // Bn*1024
  int k = idx & 1023;
  float xr = X[2*idx], xi = X[2*idx+1];
  float omega = (2.f*PI_F/Tn)*k;
  const float pref = 0.7511255444649425f;
  const float invT = 1.f/Tn;
  float* zp = Z + (size_t)idx*20;
  #pragma unroll
  for (int s=0; s<Wn; s++){
    float sc = expf(0.4f*(float)s);
    float arg = sc*omega - 6.0f;
    float psi = (k>0) ? pref*sqrtf(2.f*PI_F*sc)*expf(-0.5f*arg*arg)*invT : 0.f;
    zp[2*s]   = xr*psi;
    zp[2*s+1] = xi*psi;
  }
}

// ---------------- inverse DFT partials ----------------
__global__ void k_inv_dft(const float* __restrict__ Z, float* __restrict__ Wp){
  __shared__ float2 tw[Tn];
  __shared__ __align__(16) float zc[256*20];
  int tt = blockIdx.x, kc = blockIdx.y, b = blockIdx.z, tid = threadIdx.x;
  for (int n=tid; n<Tn; n+=256){
    float sn, cs;
    sincosf((2.f*PI_F/Tn)*n, &sn, &cs);
    tw[n] = make_float2(cs, sn);
  }
  const float* zsrc = Z + ((size_t)b*1024 + kc*256)*20;
  for (int j=tid; j<256*20; j+=256) zc[j] = zsrc[j];
  __syncthreads();
  int t = tt*256 + tid;
  float wr[Wn], wi[Wn];
  #pragma unroll
  for (int s=0;s<Wn;s++){ wr[s]=0.f; wi[s]=0.f; }
  int kbase = kc*256;
  for (int kk=0; kk<256; kk++){
    int n = ((kbase+kk)*t) & (Tn-1);
    float2 w = tw[n];
    const float4* z4 = (const float4*)(zc + kk*20);
    #pragma unroll
    for (int q=0;q<5;q++){
      float4 z = z4[q];
      wr[2*q]   += z.x*w.x - z.y*w.y;
      wi[2*q]   += z.x*w.y + z.y*w.x;
      wr[2*q+1] += z.z*w.x - z.w*w.y;
      wi[2*q+1] += z.z*w.y + z.w*w.x;
    }
  }
  float* dst = Wp + (((size_t)kc*Bn + b)*Tn + t)*20;
  #pragma unroll
  for (int s=0;s<Wn;s++){ dst[s] = wr[s]; dst[Wn+s] = wi[s]; }
}

// ---------------- combine partials + mask ----------------
__global__ void k_combine(const float* __restrict__ Wp, const int* __restrict__ mel,
                          float* __restrict__ tspec){
  int idx = blockIdx.x*256 + threadIdx.x;  // Bn*Tn*20
  int bt = idx / 20;
  int t = bt & (Tn-1), b = bt >> 11;
  float s = 0.f;
  #pragma unroll
  for (int kc=0; kc<4; kc++) s += Wp[(size_t)kc*Bn*Tn*20 + idx];
  tspec[idx] = (t < mel[b]) ? s : 0.f;
}

// ======== conv1d(k=3) bf16 MFMA GEMM — UNCHANGED from round 4 ========
template<int STAGE>
__global__ __launch_bounds__(256) void k_conv_mfma(
    const void* __restrict__ in_v, const char* __restrict__ wBimg,
    const float* __restrict__ cb, const float* __restrict__ g, const float* __restrict__ be,
    __bf16* __restrict__ h_out,
    const float* __restrict__ lw, const float* __restrict__ lb,
    const int* __restrict__ mel, float* __restrict__ pspec, float* __restrict__ p2)
{
  __shared__ char smA[66*512];
  __shared__ char smB[2][16384];
  __shared__ float part[4][64][2];
  const int tid = threadIdx.x, b = blockIdx.y, tbase = blockIdx.x*64;
  const int w = tid >> 6, l = tid & 63, lm = l & 15, lk = l >> 4;
  const int ow = w*64;

  {
    const char* src = wBimg + tid*16;
    char* dst = smB[0] + w*1024;
    #pragma unroll
    for (int r=0;r<4;r++) gld_lds16(src + r*4096, dst + r*4096);
  }
  for (int gi = tid; gi < 66*32; gi += 256){
    int r = gi >> 5, s = gi & 31;
    int t = tbase + r - 1;
    bf16x8 val;
    if ((unsigned)t < (unsigned)Tn){
      if (STAGE==1){
        const float4* src = (const float4*)((const float*)in_v + ((size_t)b*Tn + t)*256 + s*8);
        float4 a0 = src[0], a1 = src[1];
        val[0]=(__bf16)a0.x; val[1]=(__bf16)a0.y; val[2]=(__bf16)a0.z; val[3]=(__bf16)a0.w;
        val[4]=(__bf16)a1.x; val[5]=(__bf16)a1.y; val[6]=(__bf16)a1.z; val[7]=(__bf16)a1.w;
      } else {
        val = *(const bf16x8*)((const __bf16*)in_v + ((size_t)b*Tn + t)*256 + s*8);
      }
    } else {
      #pragma unroll
      for (int j=0;j<8;j++) val[j] = (__bf16)0.f;
    }
    *(bf16x8*)(smA + r*512 + ((s*16) ^ ((r&7)<<4))) = val;
  }
  __syncthreads();

  float cbv[4], gv[4], bev[4];
  #pragma unroll
  for (int nf=0; nf<4; nf++){
    int o = ow + nf*16 + lm;
    cbv[nf] = cb[o]; gv[nf] = g[o]; bev[nf] = be[o];
  }

  f32x4 acc[4][4];
  #pragma unroll
  for (int mf=0; mf<4; mf++)
    #pragma unroll
    for (int nf=0; nf<4; nf++) acc[mf][nf] = (f32x4){0.f,0.f,0.f,0.f};

  for (int s=0; s<24; s++){
    int cur = s & 1;
    if (s+1 < 24){
      const char* src = wBimg + (size_t)(s+1)*16384 + tid*16;
      char* dst = smB[cur^1] + w*1024;
      #pragma unroll
      for (int r=0;r<4;r++) gld_lds16(src + r*4096, dst + r*4096);
    }
    int k3 = s >> 3, c = s & 7;
    bf16x8 af[4], bfr[4];
    #pragma unroll
    for (int mf=0; mf<4; mf++){
      int row = mf*16 + lm + k3;
      af[mf] = *(const bf16x8*)(smA + row*512 + ((((c*4+lk)*16)) ^ ((row&7)<<4)));
    }
    #pragma unroll
    for (int nf=0; nf<4; nf++){
      int o = ow + nf*16 + lm;
      bfr[nf] = *(const bf16x8*)(smB[cur] + o*64 + ((lk*16) ^ ((o&6)<<3)));
    }
    #pragma unroll
    for (int mf=0; mf<4; mf++)
      #pragma unroll
      for (int nf=0; nf<4; nf++)
        acc[mf][nf] = __builtin_amdgcn_mfma_f32_16x16x32_bf16(af[mf], bfr[nf], acc[mf][nf], 0, 0, 0);
    __syncthreads();
  }

  #pragma unroll
  for (int mf=0; mf<4; mf++)
    #pragma unroll
    for (int nf=0; nf<4; nf++)
      #pragma unroll
      for (int j=0; j<4; j++) acc[mf][nf][j] += cbv[nf];

  #pragma unroll
  for (int mf=0; mf<4; mf++)
    #pragma unroll
    for (int j=0; j<4; j++){
      float s = acc[mf][0][j]+acc[mf][1][j]+acc[mf][2][j]+acc[mf][3][j];
      float q = acc[mf][0][j]*acc[mf][0][j] + acc[mf][1][j]*acc[mf][1][j]
              + acc[mf][2][j]*acc[mf][2][j] + acc[mf][3][j]*acc[mf][3][j];
      #pragma unroll
      for (int m=1; m<16; m<<=1){ s += __shfl_xor(s, m); q += __shfl_xor(q, m); }
      if (lm == 0){
        int row = mf*16 + lk*4 + j;
        part[w][row][0] = s;
        part[w][row][1] = q;
      }
    }
  __syncthreads();

  #pragma unroll
  for (int mf=0; mf<4; mf++)
    #pragma unroll
    for (int j=0; j<4; j++){
      int row = mf*16 + lk*4 + j;
      float s = part[0][row][0]+part[1][row][0]+part[2][row][0]+part[3][row][0];
      float q = part[0][row][1]+part[1][row][1]+part[2][row][1]+part[3][row][1];
      float mean = s * (1.f/256.f);
      float var  = q * (1.f/256.f) - mean*mean;
      float rstd = rsqrtf(var + 1e-5f);
      #pragma unroll
      for (int nf=0; nf<4; nf++){
        float h = fmaxf((acc[mf][nf][j]-mean)*rstd*gv[nf] + bev[nf], 0.f);
        int o = ow + nf*16 + lm;
        *(__bf16*)(smA + row*512 + ((((o>>3)<<4)) ^ ((row&7)<<4)) + ((o&7)<<1)) = (__bf16)h;
      }
    }
  __syncthreads();

  if (STAGE==1){
    for (int gi = tid; gi < 64*32; gi += 256){
      int r = gi >> 5, s = gi & 31;
      bf16x8 val = *(const bf16x8*)(smA + r*512 + ((s*16) ^ ((r&7)<<4)));
      *(bf16x8*)(h_out + ((size_t)b*Tn + tbase + r)*256 + s*8) = val;
    }
  } else {
    int len = mel[b];
    for (int task = tid; task < 64*22; task += 256){
      int r = task / 22, o = task - r*22;
      const float4* w4 = (const float4*)(lw + o*256);
      float s0=0.f, s1=0.f, s2=0.f, s3=0.f;
      #pragma unroll 4
      for (int f=0; f<32; f++){
        bf16x8 hv = *(const bf16x8*)(smA + r*512 + ((f*16) ^ ((r&7)<<4)));
        float4 w0 = w4[2*f], w1 = w4[2*f+1];
        s0 += (float)hv[0]*w0.x + (float)hv[4]*w1.x;
        s1 += (float)hv[1]*w0.y + (float)hv[5]*w1.y;
        s2 += (float)hv[2]*w0.z + (float)hv[6]*w1.z;
        s3 += (float)hv[3]*w0.w + (float)hv[7]*w1.w;
      }
      float sum = lb[o] + ((s0+s1)+(s2+s3));
      int t = tbase + r;
      if (o < 20) pspec[((size_t)b*Tn + t)*20 + o] = (t<len) ? sum : 0.f;
      else        p2[((size_t)b*Tn + t)*2 + (o-20)] = sum;
    }
  }
}

// ======== DIAGNOSTIC PROBES v2: isolate P (stage-A) vs E (epilogue) ========
// MODE 0: stage-A x32 (per-rep granule permutation; same address set)
// MODE 1: stage-A once + epilogue x16 (LN + h-write + copyout, verbatim)
// MODE 2: full K-loop x8 (R5 probe1, o*64 layout fixed)
// MODE 3: full K-loop x8 with NO in-loop barrier (dead data; races OK)
template<int MODE>
__global__ __launch_bounds__(256) void k_probe2(
    const float* __restrict__ in, const char* __restrict__ wBimg,
    float* __restrict__ dead)
{
  __shared__ char smA[66*512];
  __shared__ char smB[2][16384];
  __shared__ float part[4][64][2];
  const int tid = threadIdx.x, tbase = blockIdx.x*64, b = blockIdx.y;
  const int w = tid >> 6, l = tid & 63, lm = l & 15, lk = l >> 4;
  const int ow = w*64;
  const int bid = blockIdx.y*32 + blockIdx.x;
  float tsum = 0.f;

  if (MODE == 0){
    for (int rep=0; rep<32; rep++){
      int rr = rep & 31;
      for (int gi = tid; gi < 66*32; gi += 256){
        int gp = (gi & ~31) | ((gi & 31) ^ rr);   // permute lanes<->granules, same addr set
        int r = gp >> 5, s = gp & 31;
        int t = tbase + r - 1;
        bf16x8 val;
        if ((unsigned)t < (unsigned)Tn){
          const float4* src = (const float4*)(in + ((size_t)b*Tn + t)*256 + s*8);
          float4 a0 = src[0], a1 = src[1];
          val[0]=(__bf16)a0.x; val[1]=(__bf16)a0.y; val[2]=(__bf16)a0.z; val[3]=(__bf16)a0.w;
          val[4]=(__bf16)a1.x; val[5]=(__bf16)a1.y; val[6]=(__bf16)a1.z; val[7]=(__bf16)a1.w;
        } else {
          #pragma unroll
          for (int j=0;j<8;j++) val[j] = (__bf16)0.f;
        }
        *(bf16x8*)(smA + r*512 + ((s*16) ^ ((r&7)<<4))) = val;
      }
      __syncthreads();
    }
    tsum += *(float*)(smA + tid*64) + *(float*)(smB[0] + tid*4);
  }

  if (MODE == 1){
    // stage-A once (real path)
    for (int gi = tid; gi < 66*32; gi += 256){
      int r = gi >> 5, s = gi & 31;
      int t = tbase + r - 1;
      bf16x8 val;
      if ((unsigned)t < (unsigned)Tn){
        const float4* src = (const float4*)(in + ((size_t)b*Tn + t)*256 + s*8);
        float4 a0 = src[0], a1 = src[1];
        val[0]=(__bf16)a0.x; val[1]=(__bf16)a0.y; val[2]=(__bf16)a0.z; val[3]=(__bf16)a0.w;
        val[4]=(__bf16)a1.x; val[5]=(__bf16)a1.y; val[6]=(__bf16)a1.z; val[7]=(__bf16)a1.w;
      } else {
        #pragma unroll
        for (int j=0;j<8;j++) val[j] = (__bf16)0.f;
      }
      *(bf16x8*)(smA + r*512 + ((s*16) ^ ((r&7)<<4))) = val;
    }
    __syncthreads();
    // fake acc from LDS (cheap, bounded)
    f32x4 acc[4][4];
    #pragma unroll
    for (int mf=0; mf<4; mf++){
      int row = mf*16 + lm;
      bf16x8 a0 = *(const bf16x8*)(smA + row*512 + ((lk*16) ^ ((row&7)<<4)));
      #pragma unroll
      for (int nf=0; nf<4; nf++)
        #pragma unroll
        for (int j=0; j<4; j++) acc[mf][nf][j] = (float)a0[(nf+j)&7] * 0.25f;
    }
    for (int rep=0; rep<16; rep++){
      float rb = (float)rep * 1e-3f;
      #pragma unroll
      for (int mf=0; mf<4; mf++)
        #pragma unroll
        for (int nf=0; nf<4; nf++)
          #pragma unroll
          for (int j=0; j<4; j++) acc[mf][nf][j] += rb;
      // --- epilogue verbatim (gv=1, bev=0) ---
      #pragma unroll
      for (int mf=0; mf<4; mf++)
        #pragma unroll
        for (int j=0; j<4; j++){
          float s = acc[mf][0][j]+acc[mf][1][j]+acc[mf][2][j]+acc[mf][3][j];
          float q = acc[mf][0][j]*acc[mf][0][j] + acc[mf][1][j]*acc[mf][1][j]
                  + acc[mf][2][j]*acc[mf][2][j] + acc[mf][3][j]*acc[mf][3][j];
          #pragma unroll
          for (int m=1; m<16; m<<=1){ s += __shfl_xor(s, m); q += __shfl_xor(q, m); }
          if (lm == 0){
            int row = mf*16 + lk*4 + j;
            part[w][row][0] = s;
            part[w][row][1] = q;
          }
        }
      __syncthreads();
      #pragma unroll
      for (int mf=0; mf<4; mf++)
        #pragma unroll
        for (int j=0; j<4; j++){
          int row = mf*16 + lk*4 + j;
          float s = part[0][row][0]+part[1][row][0]+part[2][row][0]+part[3][row][0];
          float q = part[0][row][1]+part[1][row][1]+part[2][row][1]+part[3][row][1];
          float mean = s * (1.f/256.f);
          float var  = q * (1.f/256.f) - mean*mean;
          float rstd = rsqrtf(var + 1e-5f);
          #pragma unroll
          for (int nf=0; nf<4; nf++){
            float h = fmaxf((acc[mf][nf][j]-mean)*rstd, 0.f);
            int o = ow + nf*16 + lm;
            *(__bf16*)(smA + row*512 + ((((o>>3)<<4)) ^ ((row&7)<<4)) + ((o&7)<<1)) = (__bf16)h;
          }
        }
      __syncthreads();
      // copy-out to dead ws (rep-varying target)
      for (int gi = tid; gi < 64*32; gi += 256){
        int r = gi >> 5, s = gi & 31;
        bf16x8 val = *(const bf16x8*)(smA + r*512 + ((s*16) ^ ((r&7)<<4)));
        *(bf16x8*)((char*)dead + ((((size_t)bid*2048 + (size_t)rep*128 + gi) & 262143) * 16)) = val;
      }
    }
    tsum += *(float*)(smB[0] + tid*4);
  }

  if (MODE == 2 || MODE == 3){
    {
      const char* src = wBimg + tid*16;
      char* dst = smB[0] + w*1024;
      #pragma unroll
      for (int r=0;r<4;r++) gld_lds16(src + r*4096, dst + r*4096);
    }
    for (int gi = tid; gi < 66*32; gi += 256){
      int r = gi >> 5, s = gi & 31;
      int t = tbase + r - 1;
      bf16x8 val;
      if ((unsigned)t < (unsigned)Tn){
        const float4* src = (const float4*)(in + ((size_t)b*Tn + t)*256 + s*8);
        float4 a0 = src[0], a1 = src[1];
        val[0]=(__bf16)a0.x; val[1]=(__bf16)a0.y; val[2]=(__bf16)a0.z; val[3]=(__bf16)a0.w;
        val[4]=(__bf16)a1.x; val[5]=(__bf16)a1.y; val[6]=(__bf16)a1.z; val[7]=(__bf16)a1.w;
      } else {
        #pragma unroll
        for (int j=0;j<8;j++) val[j] = (__bf16)0.f;
      }
      *(bf16x8*)(smA + r*512 + ((s*16) ^ ((r&7)<<4))) = val;
    }
    __syncthreads();

    f32x4 acc[4][4];
    #pragma unroll
    for (int mf=0; mf<4; mf++)
      #pragma unroll
      for (int nf=0; nf<4; nf++) acc[mf][nf] = (f32x4){0.f,0.f,0.f,0.f};

    for (int rep=0; rep<8; rep++){
      int rp = rep & 1;
      for (int s=0; s<24; s++){
        int cur = s & 1;
        {
          const char* src = wBimg + (size_t)((s+1)%24)*16384 + tid*16;
          char* dst = smB[cur^1] + w*1024;
          #pragma unroll
          for (int r=0;r<4;r++) gld_lds16(src + r*4096, dst + r*4096);
        }
        int k3 = (s >> 3) + rp, c = s & 7;
        bf16x8 af[4], bfr[4];
        #pragma unroll
        for (int mf=0; mf<4; mf++){
          int row = mf*16 + lm + k3;
          af[mf] = *(const bf16x8*)(smA + row*512 + ((((c*4+lk)*16)) ^ ((row&7)<<4)));
        }
        #pragma unroll
        for (int nf=0; nf<4; nf++){
          int o = ow + nf*16 + lm;
          bfr[nf] = *(const bf16x8*)(smB[cur] + o*64 + ((lk*16) ^ ((o&6)<<3)));
        }
        #pragma unroll
        for (int mf=0; mf<4; mf++)
          #pragma unroll
          for (int nf=0; nf<4; nf++)
            acc[mf][nf] = __builtin_amdgcn_mfma_f32_16x16x32_bf16(af[mf], bfr[nf], acc[mf][nf], 0, 0, 0);
        if (MODE == 2) __syncthreads();
      }
    }
    #pragma unroll
    for (int mf=0; mf<4; mf++)
      #pragma unroll
      for (int nf=0; nf<4; nf++)
        #pragma unroll
        for (int j=0; j<4; j++) tsum += acc[mf][nf][j];
  }

  if (blockIdx.x == 0x7fffffff) dead[tid] = tsum;   // never true; defeats DCE
}

// ---------------- predictor_params ----------------
__global__ void k_pparams(const float* __restrict__ p2, float* __restrict__ ppar){
  __shared__ float r0[256], r1[256];
  int b = blockIdx.x, tid = threadIdx.x;
  float s0=0.f, s1=0.f;
  for (int t=tid; t<Tn; t+=256){
    s0 += p2[((size_t)b*Tn+t)*2];
    s1 += p2[((size_t)b*Tn+t)*2+1];
  }
  r0[tid]=s0; r1[tid]=s1; __syncthreads();
  for (int off=128; off; off>>=1){ if(tid<off){r0[tid]+=r0[tid+off]; r1[tid]+=r1[tid+off];} __syncthreads(); }
  if (tid==0){ ppar[2*b] = r0[0]*(1.f/Tn); ppar[2*b+1] = r1[0]*(1.f/Tn); }
}

// ---------------- quantize + embedding gather ----------------
__global__ void k_embed(const float* __restrict__ target, const float* __restrict__ alpha,
                        const int* __restrict__ mel, const float* __restrict__ emb,
                        float* __restrict__ out){
  int row  = blockIdx.x*4 + (threadIdx.x>>6);   // b*Tn + t
  int lane = threadIdx.x & 63;
  int b = row >> 11, t = row & (Tn-1);
  int qid = 0;
  if (t < mel[b]){
    float q = target[row]*alpha[b];
    q = fminf(fmaxf(q, 0.f), 800.f);
    qid = (int)rintf(q/3.125f) + 1;
  }
  float4 v = ((const float4*)(emb + (size_t)qid*256))[lane];
  ((float4*)(out + (size_t)row*256))[lane] = v;
}

extern "C" void kernel_launch(void* const* d_in, const int* in_sizes, int n_in,
                              void* d_out, int out_size, void* d_ws, size_t ws_size,
                              hipStream_t stream) {
  const float* x      = (const float*)d_in[0];
  const float* alpha  = (const float*)d_in[1];
  const float* target = (const float*)d_in[2];
  const int*   mel    = (const int*)  d_in[3];
  const float* w1     = (const float*)d_in[4];
  const float* b1     = (const float*)d_in[5];
  const float* g1     = (const float*)d_in[6];
  const float* be1    = (const float*)d_in[7];
  const float* w2     = (const float*)d_in[8];
  const float* b2     = (const float*)d_in[9];
  const float* g2     = (const float*)d_in[10];
  const float* be2    = (const float*)d_in[11];
  const float* lw     = (const float*)d_in[12];
  const float* lb     = (const float*)d_in[13];
  const float* emb    = (const float*)d_in[14];
  float* out = (float*)d_out;
  char*  wsb = (char*)d_ws;

  char*   wb1 = wsb + OB_WB1;
  char*   wb2 = wsb + OB_WB2;
  __bf16* h1  = (__bf16*)(wsb + OB_H1);
  float*  ms  = (float*)(wsb + OB_MS);
  float*  X   = (float*)(wsb + OB_X);
  float*  Z   = (float*)(wsb + OB_Z);
  float*  p2  = (float*)(wsb + OB_P2);
  float*  Wp  = (float*)(wsb + OB_WP);

  k_prep_w<<<1536, 256, 0, stream>>>(w1, w2, wb1, wb2);
  k_stats<<<Bn, 256, 0, stream>>>(target, mel, ms, out + O_TPAR);
  k_fwd_dft<<<Bn*64, 256, 0, stream>>>(target, mel, ms, X);
  k_zmul<<<Bn*1024/256, 256, 0, stream>>>(X, Z);
  k_inv_dft<<<dim3(Tn/256, 4, Bn), 256, 0, stream>>>(Z, Wp);
  k_combine<<<Bn*Tn*20/256, 256, 0, stream>>>(Wp, mel, out + O_TSPEC);
  k_conv_mfma<1><<<dim3(Tn/64, Bn), 256, 0, stream>>>(x, wb1, b1, g1, be1,
                                                      h1, nullptr, nullptr,
                                                      mel, nullptr, nullptr);
  k_conv_mfma<2><<<dim3(Tn/64, Bn), 256, 0, stream>>>(h1, wb2, b2, g2, be2,
                                                      nullptr, lw, lb,
                                                      mel, out + O_PSPEC, p2);
  k_pparams<<<Bn, 256, 0, stream>>>(p2, out + O_PPAR);
  k_embed<<<Bn*Tn/4, 256, 0, stream>>>(target, alpha, mel, emb, out + O_EMB);

  // ---- diagnostic probes v2 (dead writes; run after all real consumers of ws) ----
  k_probe2<0><<<dim3(Tn/64, Bn), 256, 0, stream>>>(x, wb1, Wp);
  k_probe2<1><<<dim3(Tn/64, Bn), 256, 0, stream>>>(x, wb1, Wp);
  k_probe2<2><<<dim3(Tn/64, Bn), 256, 0, stream>>>(x, wb1, Wp);
  k_probe2<3><<<dim3(Tn/64, Bn), 256, 0, stream>>>(x, wb1, Wp);
}

// Round 7
// 266.197 us; speedup vs baseline: 2.4604x; 2.4604x over previous
//
#include <hip/hip_runtime.h>
#include <hip/hip_bf16.h>
#include <math.h>

#define Bn 16
#define Tn 2048
#define Wn 10
constexpr float PI_F = 3.14159265358979323846f;

typedef __bf16 bf16x8 __attribute__((ext_vector_type(8)));
typedef float  f32x4  __attribute__((ext_vector_type(4)));

// ---- output offsets (floats) ----
constexpr size_t O_EMB   = 0;
constexpr size_t O_PSPEC = (size_t)Bn*Tn*256;            // 8388608
constexpr size_t O_PPAR  = O_PSPEC + (size_t)Bn*Tn*20;   // 9043968
constexpr size_t O_TSPEC = O_PPAR + 2*Bn;                // 9044000
constexpr size_t O_TPAR  = O_TSPEC + (size_t)Bn*Tn*20;   // 9699360

// ---- workspace BYTE offsets ----
constexpr size_t OB_WB1 = 0;                              // 24 slices x 16KB LDS image
constexpr size_t OB_WB2 = OB_WB1 + 393216;
constexpr size_t OB_H1  = OB_WB2 + 393216;                // B*T*256 bf16
constexpr size_t OB_MS  = OB_H1 + 16777216;               // 32 f32
constexpr size_t OB_X   = OB_MS + 128;                    // B*1024*2 f32
constexpr size_t OB_Z   = OB_X + 131072;                  // B*1024*20 f32
constexpr size_t OB_P2  = OB_Z + 1310720;                 // B*T*2 f32
constexpr size_t OB_WP  = OB_P2 + 262144;                 // 4*B*T*20 f32

__device__ __forceinline__ void gld_lds16(const void* g, void* l){
  __builtin_amdgcn_global_load_lds(
      (const __attribute__((address_space(1))) unsigned int*)g,
      (__attribute__((address_space(3))) unsigned int*)l, 16, 0, 0);
}

// ---- weight prep: w[o][i][k3] fp32 -> per-K-step LDS images in ws ----
__global__ void k_prep_w(const float* __restrict__ w1, const float* __restrict__ w2,
                         char* __restrict__ wb1, char* __restrict__ wb2){
  int idx = blockIdx.x*256 + threadIdx.x;     // 2 * 196608
  const float* w = w1; char* wb = wb1;
  if (idx >= 196608){ idx -= 196608; w = w2; wb = wb2; }
  int s   = idx >> 13;          // 8192 elements per slice
  int rem = idx & 8191;
  int o   = rem >> 5;
  int kk  = rem & 31;
  int k3  = s >> 3;
  int i   = (s & 7)*32 + kk;
  float v = w[((size_t)o*256 + i)*3 + k3];
  size_t off = (size_t)s*16384 + o*64 + ((((kk>>3)<<4)) ^ ((o&6)<<3)) + ((kk&7)<<1);
  *(__bf16*)(wb + off) = (__bf16)v;
}

// ---------------- per-batch stats ----------------
__global__ void k_stats(const float* __restrict__ target, const int* __restrict__ mel,
                        float* __restrict__ msbuf, float* __restrict__ tpar){
  __shared__ float red[256];
  __shared__ float mean_sh;
  int b = blockIdx.x, tid = threadIdx.x;
  const float* tg = target + (size_t)b*Tn;
  int len = mel[b];
  float lenf = (float)len;
  float s = 0.f;
  for (int t=tid; t<Tn; t+=256) s += tg[t];
  red[tid]=s; __syncthreads();
  for (int off=128; off; off>>=1){ if(tid<off) red[tid]+=red[tid+off]; __syncthreads(); }
  if (tid==0) mean_sh = red[0]/lenf;
  __syncthreads();
  float mean = mean_sh;
  float s2 = 0.f;
  for (int t=tid; t<Tn; t+=256){ float d = (t<len)?(tg[t]-mean):0.f; s2 += d*d; }
  red[tid]=s2; __syncthreads();
  for (int off=128; off; off>>=1){ if(tid<off) red[tid]+=red[tid+off]; __syncthreads(); }
  if (tid==0){
    float stdv = sqrtf(red[0]/(lenf-1.f));
    msbuf[2*b]=mean; msbuf[2*b+1]=stdv;
    tpar[2*b]=mean;  tpar[2*b+1]=stdv;
  }
}

// ---------------- forward DFT ----------------
__global__ void k_fwd_dft(const float* __restrict__ target, const int* __restrict__ mel,
                          const float* __restrict__ msbuf, float* __restrict__ X){
  __shared__ float cbuf[Tn];
  __shared__ float2 tw[Tn];
  int b = blockIdx.x >> 6, kc = blockIdx.x & 63, tid = threadIdx.x;
  int len = mel[b];
  float mean = msbuf[2*b];
  float istd = 1.f / msbuf[2*b+1];
  for (int n=tid; n<Tn; n+=256){
    float sn, cs;
    sincosf((2.f*PI_F/Tn)*n, &sn, &cs);
    tw[n] = make_float2(cs, sn);
    cbuf[n] = (n<len) ? (target[(size_t)b*Tn+n]-mean)*istd : 0.f;
  }
  __syncthreads();
  int k  = (kc<<4) | (tid>>4);
  int tl = tid & 15;
  float xr=0.f, xi=0.f;
  for (int t=tl; t<Tn; t+=16){
    int n = (k*t) & (Tn-1);
    float2 w = tw[n];
    float cv = cbuf[t];
    xr += cv*w.x;
    xi -= cv*w.y;
  }
  #pragma unroll
  for (int m=1; m<16; m<<=1){ xr += __shfl_xor(xr,m); xi += __shfl_xor(xi,m); }
  if (tl==0){ X[2*(b*1024+k)] = xr; X[2*(b*1024+k)+1] = xi; }
}

// ---------------- Z = X * psi_hat / T ----------------
__global__ void k_zmul(const float* __restrict__ X, float* __restrict__ Z){
  int idx = blockIdx.x*256 + threadIdx.x;  // Bn*1024
  int k = idx & 1023;
  float xr = X[2*idx], xi = X[2*idx+1];
  float omega = (2.f*PI_F/Tn)*k;
  const float pref = 0.7511255444649425f;
  const float invT = 1.f/Tn;
  float* zp = Z + (size_t)idx*20;
  #pragma unroll
  for (int s=0; s<Wn; s++){
    float sc = expf(0.4f*(float)s);
    float arg = sc*omega - 6.0f;
    float psi = (k>0) ? pref*sqrtf(2.f*PI_F*sc)*expf(-0.5f*arg*arg)*invT : 0.f;
    zp[2*s]   = xr*psi;
    zp[2*s+1] = xi*psi;
  }
}

// ---------------- inverse DFT partials ----------------
__global__ void k_inv_dft(const float* __restrict__ Z, float* __restrict__ Wp){
  __shared__ float2 tw[Tn];
  __shared__ __align__(16) float zc[256*20];
  int tt = blockIdx.x, kc = blockIdx.y, b = blockIdx.z, tid = threadIdx.x;
  for (int n=tid; n<Tn; n+=256){
    float sn, cs;
    sincosf((2.f*PI_F/Tn)*n, &sn, &cs);
    tw[n] = make_float2(cs, sn);
  }
  const float* zsrc = Z + ((size_t)b*1024 + kc*256)*20;
  for (int j=tid; j<256*20; j+=256) zc[j] = zsrc[j];
  __syncthreads();
  int t = tt*256 + tid;
  float wr[Wn], wi[Wn];
  #pragma unroll
  for (int s=0;s<Wn;s++){ wr[s]=0.f; wi[s]=0.f; }
  int kbase = kc*256;
  for (int kk=0; kk<256; kk++){
    int n = ((kbase+kk)*t) & (Tn-1);
    float2 w = tw[n];
    const float4* z4 = (const float4*)(zc + kk*20);
    #pragma unroll
    for (int q=0;q<5;q++){
      float4 z = z4[q];
      wr[2*q]   += z.x*w.x - z.y*w.y;
      wi[2*q]   += z.x*w.y + z.y*w.x;
      wr[2*q+1] += z.z*w.x - z.w*w.y;
      wi[2*q+1] += z.z*w.y + z.w*w.x;
    }
  }
  float* dst = Wp + (((size_t)kc*Bn + b)*Tn + t)*20;
  #pragma unroll
  for (int s=0;s<Wn;s++){ dst[s] = wr[s]; dst[Wn+s] = wi[s]; }
}

// ---------------- combine partials + mask ----------------
__global__ void k_combine(const float* __restrict__ Wp, const int* __restrict__ mel,
                          float* __restrict__ tspec){
  int idx = blockIdx.x*256 + threadIdx.x;  // Bn*Tn*20
  int bt = idx / 20;
  int t = bt & (Tn-1), b = bt >> 11;
  float s = 0.f;
  #pragma unroll
  for (int kc=0; kc<4; kc++) s += Wp[(size_t)kc*Bn*Tn*20 + idx];
  tspec[idx] = (t < mel[b]) ? s : 0.f;
}

// ======== conv1d(k=3) bf16 MFMA GEMM; stage-A now MLP-batched (R7) ========
template<int STAGE>
__global__ __launch_bounds__(256, 2) void k_conv_mfma(
    const void* __restrict__ in_v, const char* __restrict__ wBimg,
    const float* __restrict__ cb, const float* __restrict__ g, const float* __restrict__ be,
    __bf16* __restrict__ h_out,
    const float* __restrict__ lw, const float* __restrict__ lb,
    const int* __restrict__ mel, float* __restrict__ pspec, float* __restrict__ p2)
{
  __shared__ char smA[66*512];
  __shared__ char smB[2][16384];
  __shared__ float part[4][64][2];
  const int tid = threadIdx.x, b = blockIdx.y, tbase = blockIdx.x*64;
  const int w = tid >> 6, l = tid & 63, lm = l & 15, lk = l >> 4;
  const int ow = w*64;

  // ---- stage-A phase 1: issue ALL input loads to registers (clamped addr) ----
  float4 va[8], vb[8];
  bf16x8 vv[8];
  float4 ta0, ta1; bf16x8 tv;                 // tail granule (wave 0 only)
  #pragma unroll
  for (int j=0; j<8; j++){
    int gi = tid + j*256;
    int r = gi >> 5, s = gi & 31;
    int t = tbase + r - 1;
    int tc = min(max(t, 0), Tn-1);
    if (STAGE==1){
      const float4* src = (const float4*)((const float*)in_v + ((size_t)b*Tn + tc)*256 + s*8);
      va[j] = src[0]; vb[j] = src[1];
    } else {
      vv[j] = *(const bf16x8*)((const __bf16*)in_v + ((size_t)b*Tn + tc)*256 + s*8);
    }
  }
  if (tid < 64){
    int gi = 2048 + tid;
    int r = gi >> 5, s = gi & 31;
    int t = tbase + r - 1;
    int tc = min(max(t, 0), Tn-1);
    if (STAGE==1){
      const float4* src = (const float4*)((const float*)in_v + ((size_t)b*Tn + tc)*256 + s*8);
      ta0 = src[0]; ta1 = src[1];
    } else {
      tv = *(const bf16x8*)((const __bf16*)in_v + ((size_t)b*Tn + tc)*256 + s*8);
    }
  }
  // ---- issue async stage of B slice 0 (queued behind A loads) ----
  {
    const char* src = wBimg + tid*16;
    char* dst = smB[0] + w*1024;
    #pragma unroll
    for (int r=0;r<4;r++) gld_lds16(src + r*4096, dst + r*4096);
  }
  // ---- stage-A phase 2: cvt + swizzled LDS writes (one wait, then 8 writes) ----
  #pragma unroll
  for (int j=0; j<8; j++){
    int gi = tid + j*256;
    int r = gi >> 5, s = gi & 31;
    int t = tbase + r - 1;
    bool ok = ((unsigned)t < (unsigned)Tn);
    bf16x8 val;
    if (STAGE==1){
      val[0]=(__bf16)va[j].x; val[1]=(__bf16)va[j].y; val[2]=(__bf16)va[j].z; val[3]=(__bf16)va[j].w;
      val[4]=(__bf16)vb[j].x; val[5]=(__bf16)vb[j].y; val[6]=(__bf16)vb[j].z; val[7]=(__bf16)vb[j].w;
    } else {
      val = vv[j];
    }
    if (!ok){
      #pragma unroll
      for (int q=0;q<8;q++) val[q] = (__bf16)0.f;
    }
    *(bf16x8*)(smA + r*512 + ((s*16) ^ ((r&7)<<4))) = val;
  }
  if (tid < 64){
    int gi = 2048 + tid;
    int r = gi >> 5, s = gi & 31;
    int t = tbase + r - 1;
    bool ok = ((unsigned)t < (unsigned)Tn);
    bf16x8 val;
    if (STAGE==1){
      val[0]=(__bf16)ta0.x; val[1]=(__bf16)ta0.y; val[2]=(__bf16)ta0.z; val[3]=(__bf16)ta0.w;
      val[4]=(__bf16)ta1.x; val[5]=(__bf16)ta1.y; val[6]=(__bf16)ta1.z; val[7]=(__bf16)ta1.w;
    } else {
      val = tv;
    }
    if (!ok){
      #pragma unroll
      for (int q=0;q<8;q++) val[q] = (__bf16)0.f;
    }
    *(bf16x8*)(smA + r*512 + ((s*16) ^ ((r&7)<<4))) = val;
  }
  __syncthreads();   // drains vmcnt (slice0 DMA) + lgkmcnt (A writes)

  float cbv[4], gv[4], bev[4];
  #pragma unroll
  for (int nf=0; nf<4; nf++){
    int o = ow + nf*16 + lm;
    cbv[nf] = cb[o]; gv[nf] = g[o]; bev[nf] = be[o];
  }

  f32x4 acc[4][4];
  #pragma unroll
  for (int mf=0; mf<4; mf++)
    #pragma unroll
    for (int nf=0; nf<4; nf++) acc[mf][nf] = (f32x4){0.f,0.f,0.f,0.f};

  for (int s=0; s<24; s++){
    int cur = s & 1;
    if (s+1 < 24){
      const char* src = wBimg + (size_t)(s+1)*16384 + tid*16;
      char* dst = smB[cur^1] + w*1024;
      #pragma unroll
      for (int r=0;r<4;r++) gld_lds16(src + r*4096, dst + r*4096);
    }
    int k3 = s >> 3, c = s & 7;
    bf16x8 af[4], bfr[4];
    #pragma unroll
    for (int mf=0; mf<4; mf++){
      int row = mf*16 + lm + k3;
      af[mf] = *(const bf16x8*)(smA + row*512 + ((((c*4+lk)*16)) ^ ((row&7)<<4)));
    }
    #pragma unroll
    for (int nf=0; nf<4; nf++){
      int o = ow + nf*16 + lm;
      bfr[nf] = *(const bf16x8*)(smB[cur] + o*64 + ((lk*16) ^ ((o&6)<<3)));
    }
    #pragma unroll
    for (int mf=0; mf<4; mf++)
      #pragma unroll
      for (int nf=0; nf<4; nf++)
        acc[mf][nf] = __builtin_amdgcn_mfma_f32_16x16x32_bf16(af[mf], bfr[nf], acc[mf][nf], 0, 0, 0);
    __syncthreads();
  }

  #pragma unroll
  for (int mf=0; mf<4; mf++)
    #pragma unroll
    for (int nf=0; nf<4; nf++)
      #pragma unroll
      for (int j=0; j<4; j++) acc[mf][nf][j] += cbv[nf];

  #pragma unroll
  for (int mf=0; mf<4; mf++)
    #pragma unroll
    for (int j=0; j<4; j++){
      float s = acc[mf][0][j]+acc[mf][1][j]+acc[mf][2][j]+acc[mf][3][j];
      float q = acc[mf][0][j]*acc[mf][0][j] + acc[mf][1][j]*acc[mf][1][j]
              + acc[mf][2][j]*acc[mf][2][j] + acc[mf][3][j]*acc[mf][3][j];
      #pragma unroll
      for (int m=1; m<16; m<<=1){ s += __shfl_xor(s, m); q += __shfl_xor(q, m); }
      if (lm == 0){
        int row = mf*16 + lk*4 + j;
        part[w][row][0] = s;
        part[w][row][1] = q;
      }
    }
  __syncthreads();

  #pragma unroll
  for (int mf=0; mf<4; mf++)
    #pragma unroll
    for (int j=0; j<4; j++){
      int row = mf*16 + lk*4 + j;
      float s = part[0][row][0]+part[1][row][0]+part[2][row][0]+part[3][row][0];
      float q = part[0][row][1]+part[1][row][1]+part[2][row][1]+part[3][row][1];
      float mean = s * (1.f/256.f);
      float var  = q * (1.f/256.f) - mean*mean;
      float rstd = rsqrtf(var + 1e-5f);
      #pragma unroll
      for (int nf=0; nf<4; nf++){
        float h = fmaxf((acc[mf][nf][j]-mean)*rstd*gv[nf] + bev[nf], 0.f);
        int o = ow + nf*16 + lm;
        *(__bf16*)(smA + row*512 + ((((o>>3)<<4)) ^ ((row&7)<<4)) + ((o&7)<<1)) = (__bf16)h;
      }
    }
  __syncthreads();

  if (STAGE==1){
    for (int gi = tid; gi < 64*32; gi += 256){
      int r = gi >> 5, s = gi & 31;
      bf16x8 val = *(const bf16x8*)(smA + r*512 + ((s*16) ^ ((r&7)<<4)));
      *(bf16x8*)(h_out + ((size_t)b*Tn + tbase + r)*256 + s*8) = val;
    }
  } else {
    int len = mel[b];
    for (int task = tid; task < 64*22; task += 256){
      int r = task / 22, o = task - r*22;
      const float4* w4 = (const float4*)(lw + o*256);
      float s0=0.f, s1=0.f, s2=0.f, s3=0.f;
      #pragma unroll 4
      for (int f=0; f<32; f++){
        bf16x8 hv = *(const bf16x8*)(smA + r*512 + ((f*16) ^ ((r&7)<<4)));
        float4 w0 = w4[2*f], w1 = w4[2*f+1];
        s0 += (float)hv[0]*w0.x + (float)hv[4]*w1.x;
        s1 += (float)hv[1]*w0.y + (float)hv[5]*w1.y;
        s2 += (float)hv[2]*w0.z + (float)hv[6]*w1.z;
        s3 += (float)hv[3]*w0.w + (float)hv[7]*w1.w;
      }
      float sum = lb[o] + ((s0+s1)+(s2+s3));
      int t = tbase + r;
      if (o < 20) pspec[((size_t)b*Tn + t)*20 + o] = (t<len) ? sum : 0.f;
      else        p2[((size_t)b*Tn + t)*2 + (o-20)] = sum;
    }
  }
}

// ======== COLD PROBE: OLD interleaved stage-A only (1 tile, dead output) ========
__global__ __launch_bounds__(256, 2) void k_probeA(
    const float* __restrict__ in, float* __restrict__ dead)
{
  __shared__ char smA[66*512];
  __shared__ char smB[2][16384];
  __shared__ float part[4][64][2];
  const int tid = threadIdx.x, tbase = blockIdx.x*64, b = blockIdx.y;
  // old-style interleaved load->cvt->ds_write staging (the R6-and-earlier pattern)
  for (int gi = tid; gi < 66*32; gi += 256){
    int r = gi >> 5, s = gi & 31;
    int t = tbase + r - 1;
    bf16x8 val;
    if ((unsigned)t < (unsigned)Tn){
      const float4* src = (const float4*)(in + ((size_t)b*Tn + t)*256 + s*8);
      float4 a0 = src[0], a1 = src[1];
      val[0]=(__bf16)a0.x; val[1]=(__bf16)a0.y; val[2]=(__bf16)a0.z; val[3]=(__bf16)a0.w;
      val[4]=(__bf16)a1.x; val[5]=(__bf16)a1.y; val[6]=(__bf16)a1.z; val[7]=(__bf16)a1.w;
    } else {
      #pragma unroll
      for (int j=0;j<8;j++) val[j] = (__bf16)0.f;
    }
    *(bf16x8*)(smA + r*512 + ((s*16) ^ ((r&7)<<4))) = val;
  }
  __syncthreads();
  float tsum = *(float*)(smA + tid*64) + *(float*)(smB[0] + tid*4) + part[0][tid&63][0];
  if (blockIdx.x == 0x7fffffff) dead[tid] = tsum;   // never true; defeats DCE
}

// ---------------- predictor_params ----------------
__global__ void k_pparams(const float* __restrict__ p2, float* __restrict__ ppar){
  __shared__ float r0[256], r1[256];
  int b = blockIdx.x, tid = threadIdx.x;
  float s0=0.f, s1=0.f;
  for (int t=tid; t<Tn; t+=256){
    s0 += p2[((size_t)b*Tn+t)*2];
    s1 += p2[((size_t)b*Tn+t)*2+1];
  }
  r0[tid]=s0; r1[tid]=s1; __syncthreads();
  for (int off=128; off; off>>=1){ if(tid<off){r0[tid]+=r0[tid+off]; r1[tid]+=r1[tid+off];} __syncthreads(); }
  if (tid==0){ ppar[2*b] = r0[0]*(1.f/Tn); ppar[2*b+1] = r1[0]*(1.f/Tn); }
}

// ---------------- quantize + embedding gather ----------------
__global__ void k_embed(const float* __restrict__ target, const float* __restrict__ alpha,
                        const int* __restrict__ mel, const float* __restrict__ emb,
                        float* __restrict__ out){
  int row  = blockIdx.x*4 + (threadIdx.x>>6);   // b*Tn + t
  int lane = threadIdx.x & 63;
  int b = row >> 11, t = row & (Tn-1);
  int qid = 0;
  if (t < mel[b]){
    float q = target[row]*alpha[b];
    q = fminf(fmaxf(q, 0.f), 800.f);
    qid = (int)rintf(q/3.125f) + 1;
  }
  float4 v = ((const float4*)(emb + (size_t)qid*256))[lane];
  ((float4*)(out + (size_t)row*256))[lane] = v;
}

extern "C" void kernel_launch(void* const* d_in, const int* in_sizes, int n_in,
                              void* d_out, int out_size, void* d_ws, size_t ws_size,
                              hipStream_t stream) {
  const float* x      = (const float*)d_in[0];
  const float* alpha  = (const float*)d_in[1];
  const float* target = (const float*)d_in[2];
  const int*   mel    = (const int*)  d_in[3];
  const float* w1     = (const float*)d_in[4];
  const float* b1     = (const float*)d_in[5];
  const float* g1     = (const float*)d_in[6];
  const float* be1    = (const float*)d_in[7];
  const float* w2     = (const float*)d_in[8];
  const float* b2     = (const float*)d_in[9];
  const float* g2     = (const float*)d_in[10];
  const float* be2    = (const float*)d_in[11];
  const float* lw     = (const float*)d_in[12];
  const float* lb     = (const float*)d_in[13];
  const float* emb    = (const float*)d_in[14];
  float* out = (float*)d_out;
  char*  wsb = (char*)d_ws;

  char*   wb1 = wsb + OB_WB1;
  char*   wb2 = wsb + OB_WB2;
  __bf16* h1  = (__bf16*)(wsb + OB_H1);
  float*  ms  = (float*)(wsb + OB_MS);
  float*  X   = (float*)(wsb + OB_X);
  float*  Z   = (float*)(wsb + OB_Z);
  float*  p2  = (float*)(wsb + OB_P2);
  float*  Wp  = (float*)(wsb + OB_WP);

  k_prep_w<<<1536, 256, 0, stream>>>(w1, w2, wb1, wb2);
  k_stats<<<Bn, 256, 0, stream>>>(target, mel, ms, out + O_TPAR);
  k_fwd_dft<<<Bn*64, 256, 0, stream>>>(target, mel, ms, X);
  k_zmul<<<Bn*1024/256, 256, 0, stream>>>(X, Z);
  k_inv_dft<<<dim3(Tn/256, 4, Bn), 256, 0, stream>>>(Z, Wp);
  k_combine<<<Bn*Tn*20/256, 256, 0, stream>>>(Wp, mel, out + O_TSPEC);
  k_conv_mfma<1><<<dim3(Tn/64, Bn), 256, 0, stream>>>(x, wb1, b1, g1, be1,
                                                      h1, nullptr, nullptr,
                                                      mel, nullptr, nullptr);
  k_conv_mfma<2><<<dim3(Tn/64, Bn), 256, 0, stream>>>(h1, wb2, b2, g2, be2,
                                                      nullptr, lw, lb,
                                                      mel, out + O_PSPEC, p2);
  k_pparams<<<Bn, 256, 0, stream>>>(p2, out + O_PPAR);
  k_embed<<<Bn*Tn/4, 256, 0, stream>>>(target, alpha, mel, emb, out + O_EMB);

  // ---- cold probe (old staging pattern, dead output) ----
  k_probeA<<<dim3(Tn/64, Bn), 256, 0, stream>>>(x, Wp);
}